// Round 1
// baseline (72.765 us; speedup 1.0000x reference)
//
#include <hip/hip_runtime.h>
#include <cmath>

#define T_LEN 8192
#define B_ROWS 128
#define ND 360          // MAX_DELAY - MIN_DELAY
#define MIN_DELAY_C 60
#define BLOCK 512

__global__ __launch_bounds__(BLOCK) void ks_resonator_kernel(
    const float* __restrict__ excitation,     // (128,1,8192)
    const float* __restrict__ gumbel,         // (360,)
    const float* __restrict__ delay_param,    // (360,)
    const float* __restrict__ feedback_gain,  // (1,)
    const float* __restrict__ refl,           // (2,)
    float* __restrict__ out)                  // (128,1,8192)
{
    __shared__ float y[T_LEN];            // 32 KB: row buffer, in-place x -> y
    __shared__ float red_v[BLOCK];
    __shared__ int   red_i[BLOCK];
    __shared__ float s_a1, s_a2;
    __shared__ int   s_lagA, s_lagB;

    const int tid = threadIdx.x;
    const int row = blockIdx.x;

    // ---- redundant per-block: argmax over (delay_param + gumbel), 360 elems ----
    float v = -INFINITY; int idx = 0;
    if (tid < ND) { v = delay_param[tid] + gumbel[tid]; idx = tid; }
    red_v[tid] = v; red_i[tid] = idx;
    __syncthreads();
    for (int off = BLOCK / 2; off > 0; off >>= 1) {
        if (tid < off) {
            float v2 = red_v[tid + off]; int i2 = red_i[tid + off];
            float v1 = red_v[tid];       int i1 = red_i[tid];
            // jnp.argmax: first occurrence wins ties
            if (v2 > v1 || (v2 == v1 && i2 < i1)) { red_v[tid] = v2; red_i[tid] = i2; }
        }
        __syncthreads();
    }

    if (tid == 0) {
        int p = red_i[0];
        // rc = tanh(reflection_coeffs); k = resonant_activation(rc, 0) = tanh(rc)
        float k1 = tanhf(tanhf(refl[0]));
        float k2 = tanhf(tanhf(refl[1]));
        float a1 = k1 * (1.0f - k2);
        float a2 = fminf(fmaxf(k2, -0.999f), 0.999f);
        float bound = 0.999f - fabsf(a2);
        a1 = fminf(fmaxf(a1, -bound), bound);
        float fg = feedback_gain[0];
        float g = powf(1.0f / (1.0f + expf(-fg)), 0.45f);
        a1 *= g; a2 *= g;
        int p2 = (p + 1) % ND;   // jnp.roll(one_hot, 1)
        s_a1 = a1; s_a2 = a2;
        s_lagA = MIN_DELAY_C + p + 1;   // coeff index 60+p multiplies y[t-1-(60+p)]
        s_lagB = MIN_DELAY_C + p2 + 1;
    }
    __syncthreads();

    const float a1 = s_a1, a2 = s_a2;
    const int lagA = s_lagA, lagB = s_lagB;
    const int C = (lagA < lagB) ? lagA : lagB;   // safe parallel-chunk width (>= 61)

    // ---- load excitation row into LDS ----
    const float* x = excitation + (size_t)row * T_LEN;
    for (int i = tid; i < T_LEN; i += BLOCK) y[i] = x[i];
    __syncthreads();

    // ---- chunked in-place recurrence: y[t] = x[t] - a1*y[t-lagA] - a2*y[t-lagB]
    for (int pos = 0; pos < T_LEN; pos += C) {
        int end = pos + C; if (end > T_LEN) end = T_LEN;
        for (int j = pos + tid; j < end; j += BLOCK) {
            float ya = (j >= lagA) ? y[j - lagA] : 0.0f;
            float yb = (j >= lagB) ? y[j - lagB] : 0.0f;
            y[j] = y[j] - a1 * ya - a2 * yb;
        }
        __syncthreads();
    }

    // ---- store ----
    float* o = out + (size_t)row * T_LEN;
    for (int i = tid; i < T_LEN; i += BLOCK) o[i] = y[i];
}

extern "C" void kernel_launch(void* const* d_in, const int* in_sizes, int n_in,
                              void* d_out, int out_size, void* d_ws, size_t ws_size,
                              hipStream_t stream) {
    const float* excitation    = (const float*)d_in[0];
    const float* gumbel        = (const float*)d_in[1];
    const float* delay_param   = (const float*)d_in[2];
    const float* feedback_gain = (const float*)d_in[3];
    const float* refl          = (const float*)d_in[4];
    float* out = (float*)d_out;

    ks_resonator_kernel<<<B_ROWS, BLOCK, 0, stream>>>(
        excitation, gumbel, delay_param, feedback_gain, refl, out);
}